// Round 2
// 2229.681 us; speedup vs baseline: 1.2605x; 1.2605x over previous
//
#include <hip/hip_runtime.h>
#include <cmath>

#define T_DIM 2048
#define H_DIM 2048
#define NH    16
#define NKV   4
#define HD    128
#define NE    8
#define I_DIM 4096
#define QS    2048   // NH*HD
#define KVS   512    // NKV*HD
#define QKV_N 3072   // QS + 2*KVS
#define PADMAX 3072  // T + NE*127 rounded up to 128-blocks
#define MAXRB  24    // PADMAX/128

#define BM 128
#define BN 128
#define BK 32
#define LP 40        // LDS row pitch in shorts (80B: 16B-aligned, 2-way-max frag-read conflicts)

constexpr int ST_PLAIN = 0, ST_RESID = 1, ST_ACCUM = 2, ST_SCATTER = 3, ST_SILU = 4;

typedef __attribute__((ext_vector_type(8))) short bf16x8;
typedef __attribute__((ext_vector_type(4))) float f32x4;

__device__ __forceinline__ unsigned short f2bf(float f) {
  unsigned u = __float_as_uint(f);
  u += 0x7fff + ((u >> 16) & 1);  // RNE
  return (unsigned short)(u >> 16);
}
__device__ __forceinline__ float bf2f(unsigned short h) {
  return __uint_as_float(((unsigned)h) << 16);
}

__device__ __forceinline__ float waveReduceSum(float v) {
#pragma unroll
  for (int o = 32; o; o >>= 1) v += __shfl_xor(v, o, 64);
  return v;
}

// ---------------- rmsnorm over H=2048 (one block per token) ----------------
// Always writes bf16 hi; optionally fp32 (router needs exact y) and bf16 lo (split GEMM A).
template <bool WF32, bool WLO>
__global__ __launch_bounds__(256) void rmsnorm_kernel(const float* __restrict__ in,
                                                      const float* __restrict__ w,
                                                      float* __restrict__ outf,
                                                      ushort* __restrict__ ohi,
                                                      ushort* __restrict__ olo) {
  int t = blockIdx.x, tid = threadIdx.x;
  const float* row = in + (size_t)t * H_DIM;
  float4 a = *(const float4*)(row + tid * 4);
  float4 b = *(const float4*)(row + (tid + 256) * 4);
  float ss = a.x * a.x + a.y * a.y + a.z * a.z + a.w * a.w +
             b.x * b.x + b.y * b.y + b.z * b.z + b.w * b.w;
  __shared__ float red[4];
  float sw = waveReduceSum(ss);
  if ((tid & 63) == 0) red[tid >> 6] = sw;
  __syncthreads();
  float tot = red[0] + red[1] + red[2] + red[3];
  float r = rsqrtf(tot / (float)H_DIM + 1e-5f);
  float4 wa = *(const float4*)(w + tid * 4);
  float4 wb = *(const float4*)(w + (tid + 256) * 4);
  float4 ra = make_float4(a.x * r * wa.x, a.y * r * wa.y, a.z * r * wa.z, a.w * r * wa.w);
  float4 rb = make_float4(b.x * r * wb.x, b.y * r * wb.y, b.z * r * wb.z, b.w * r * wb.w);
  size_t o0 = (size_t)t * H_DIM + tid * 4;
  size_t o1 = (size_t)t * H_DIM + (tid + 256) * 4;
  if constexpr (WF32) {
    *(float4*)(outf + o0) = ra;
    *(float4*)(outf + o1) = rb;
  }
  ushort4 ha = make_ushort4(f2bf(ra.x), f2bf(ra.y), f2bf(ra.z), f2bf(ra.w));
  ushort4 hb = make_ushort4(f2bf(rb.x), f2bf(rb.y), f2bf(rb.z), f2bf(rb.w));
  *(ushort4*)(ohi + o0) = ha;
  *(ushort4*)(ohi + o1) = hb;
  if constexpr (WLO) {
    ushort4 la = make_ushort4(f2bf(ra.x - bf2f(ha.x)), f2bf(ra.y - bf2f(ha.y)),
                              f2bf(ra.z - bf2f(ha.z)), f2bf(ra.w - bf2f(ha.w)));
    ushort4 lb = make_ushort4(f2bf(rb.x - bf2f(hb.x)), f2bf(rb.y - bf2f(hb.y)),
                              f2bf(rb.z - bf2f(hb.z)), f2bf(rb.w - bf2f(hb.w)));
    *(ushort4*)(olo + o0) = la;
    *(ushort4*)(olo + o1) = lb;
  }
}

// -------- rope (theta=5e5) then rmsnorm over full q (2048) / k (512) --------
// Emits bf16 hi+lo for Q [t][2048] and K [t][512]; fp32 qkv is left untouched (V only).
__global__ __launch_bounds__(256) void rope_norm_kernel(const float* __restrict__ qkv,
                                                        const int* __restrict__ pos,
                                                        const float* __restrict__ qw,
                                                        const float* __restrict__ kw,
                                                        ushort* __restrict__ qbh,
                                                        ushort* __restrict__ qbl,
                                                        ushort* __restrict__ kbh,
                                                        ushort* __restrict__ kbl) {
  int t = blockIdx.x, tid = threadIdx.x;
  const float* row = qkv + (size_t)t * QKV_N;
  float fpos = (float)pos[t];
  const float k2 = 18.931568569324174f / 64.f;  // log2(theta)/64
  float q1[4], q2[4];
  float ss = 0.f;
#pragma unroll
  for (int i = 0; i < 4; i++) {
    int p = tid + 256 * i;
    int hh = p >> 6, d = p & 63;
    float fr = fpos * exp2f(-(float)d * k2);
    float s, c;
    sincosf(fr, &s, &c);
    float x1 = row[hh * 128 + d];
    float x2 = row[hh * 128 + 64 + d];
    q1[i] = x1 * c - x2 * s;
    q2[i] = x2 * c + x1 * s;
    ss += q1[i] * q1[i] + q2[i] * q2[i];
  }
  __shared__ float redA[4], redB[4];
  int lane = tid & 63, wid = tid >> 6;
  float sw = waveReduceSum(ss);
  if (lane == 0) redA[wid] = sw;
  int hk = tid >> 6, dk = tid & 63;
  float frk = fpos * exp2f(-(float)dk * k2);
  float sk, ck;
  sincosf(frk, &sk, &ck);
  const float* krow = row + QS;
  float kx1 = krow[hk * 128 + dk], kx2 = krow[hk * 128 + 64 + dk];
  float k1v = kx1 * ck - kx2 * sk;
  float k2v = kx2 * ck + kx1 * sk;
  float ssk = waveReduceSum(k1v * k1v + k2v * k2v);
  if (lane == 0) redB[wid] = ssk;
  __syncthreads();
  float rq = rsqrtf((redA[0] + redA[1] + redA[2] + redA[3]) / (float)QS + 1e-5f);
  float rk = rsqrtf((redB[0] + redB[1] + redB[2] + redB[3]) / (float)KVS + 1e-5f);
  size_t qb = (size_t)t * QS;
#pragma unroll
  for (int i = 0; i < 4; i++) {
    int p = tid + 256 * i;
    int hh = p >> 6, d = p & 63;
    int i1 = hh * 128 + d, i2 = i1 + 64;
    float v1 = q1[i] * rq * qw[i1];
    float v2 = q2[i] * rq * qw[i2];
    ushort h1 = f2bf(v1), h2 = f2bf(v2);
    qbh[qb + i1] = h1;
    qbl[qb + i1] = f2bf(v1 - bf2f(h1));
    qbh[qb + i2] = h2;
    qbl[qb + i2] = f2bf(v2 - bf2f(h2));
  }
  {
    int i1 = hk * 128 + dk, i2 = i1 + 64;
    float v1 = k1v * rk * kw[i1];
    float v2 = k2v * rk * kw[i2];
    size_t kb = (size_t)t * KVS;
    ushort h1 = f2bf(v1), h2 = f2bf(v2);
    kbh[kb + i1] = h1;
    kbl[kb + i1] = f2bf(v1 - bf2f(h1));
    kbh[kb + i2] = h2;
    kbl[kb + i2] = f2bf(v2 - bf2f(h2));
  }
}

// ---------------- V transpose + bf16 hi/lo split: Vt[d_glob][t] ----------------
// blockIdx.x = d_glob (0..511); thread covers 8 consecutive t. Reads are scalar
// (L2-resident, just written by qkv GEMM); writes are fully coalesced 16B.
__global__ __launch_bounds__(256) void vtrans_kernel(const float* __restrict__ qkv,
                                                     ushort* __restrict__ vth,
                                                     ushort* __restrict__ vtl) {
  int d = blockIdx.x;
  int t0 = threadIdx.x * 8;
  const float* src = qkv + QS + KVS + d;
  ushort hh[8], ll[8];
#pragma unroll
  for (int j = 0; j < 8; j++) {
    float v = src[(size_t)(t0 + j) * QKV_N];
    hh[j] = f2bf(v);
    ll[j] = f2bf(v - bf2f(hh[j]));
  }
  ushort* dh = vth + (size_t)d * T_DIM + t0;
  ushort* dl = vtl + (size_t)d * T_DIM + t0;
  *(ushort4*)dh = make_ushort4(hh[0], hh[1], hh[2], hh[3]);
  *(ushort4*)(dh + 4) = make_ushort4(hh[4], hh[5], hh[6], hh[7]);
  *(ushort4*)dl = make_ushort4(ll[0], ll[1], ll[2], ll[3]);
  *(ushort4*)(dl + 4) = make_ushort4(ll[4], ll[5], ll[6], ll[7]);
}

// ---------------- GQA causal flash attention, MFMA (bf16 split), writes bf16 hi+lo --------
// 512 blocks: each = (head h, 64-row Q tile). 4 waves; wave owns 16 Q rows.
// QK^T: 3-term split (fp32-class scores). PV: P bf16 x (Vhi + Vlo).
// K and V TIME-SHARE one hi/lo LDS buffer (K phase then V phase, 4 barriers/iter):
// total static LDS = 43.5 KB (< 64 KB limit, 3 blocks/CU by LDS).
// Block remap: XCD pair hosts one KV group (K+V bf16 = 2MB fits 4MB L2);
// CU pairing heavy+light Q-tiles sums to exactly 33 iterations everywhere.
#define KLP 132  // K view pitch (shorts), 64 rows
#define VLP 68   // Vt view pitch (shorts), 128 rows
#define PLP 68   // P pitch
__global__ __launch_bounds__(256) void attn_mfma(
    const ushort* __restrict__ qh, const ushort* __restrict__ ql,
    const ushort* __restrict__ kh, const ushort* __restrict__ kl,
    const ushort* __restrict__ vh, const ushort* __restrict__ vl,
    ushort* __restrict__ ohi, ushort* __restrict__ olo) {
  __shared__ short KVh[128 * VLP];  // 8704 shorts; K view needs 64*KLP = 8448
  __shared__ short KVl[128 * VLP];
  __shared__ short Ps[4][16 * PLP];
  int bx = blockIdx.x;
  int xcd = bx & 7, slot = bx >> 3;        // bx%8 round-robins XCDs
  int g = xcd >> 1, par = xcd & 1;
  int h = g * 4 + (slot & 3);
  int srank = slot >> 2;                   // 0..15
  int qt = (srank < 8) ? (31 - par - 2 * srank) : (par + 2 * (srank - 8));
  int q0 = qt * 64;
  int tid = threadIdx.x, lane = tid & 63, wid = tid >> 6;
  int l15 = lane & 15, quad = lane >> 4;
  // Q fragments (A layout: row = lane&15, k = quad*8 + i), hi+lo
  bf16x8 qfh[4], qfl[4];
  {
    size_t qoff = (size_t)(q0 + wid * 16 + l15) * QS + h * HD + quad * 8;
    const ushort* ph = qh + qoff;
    const ushort* pl = ql + qoff;
#pragma unroll
    for (int ks = 0; ks < 4; ks++) {
      qfh[ks] = *(const bf16x8*)(const void*)(ph + ks * 32);
      qfl[ks] = *(const bf16x8*)(const void*)(pl + ks * 32);
    }
  }
  f32x4 o[8];
#pragma unroll
  for (int i = 0; i < 8; i++) o[i] = (f32x4){0.f, 0.f, 0.f, 0.f};
  float m[4] = {-1e30f, -1e30f, -1e30f, -1e30f};
  float l[4] = {0.f, 0.f, 0.f, 0.f};
  const float scale = 0.08838834764831845f;
  for (int s0 = 0; s0 <= q0; s0 += 64) {
    __syncthreads();  // prev iter's PV reads done before K overwrite
    // ---- stage K hi/lo: 64 rows x 128 shorts each ----
#pragma unroll
    for (int it = 0; it < 4; it++) {
      int c = it * 256 + tid;
      int r = c >> 4, off = (c & 15) * 8;
      size_t ga = (size_t)(s0 + r) * KVS + g * HD + off;
      *(uint4*)(void*)&KVh[r * KLP + off] = *(const uint4*)(const void*)(kh + ga);
      *(uint4*)(void*)&KVl[r * KLP + off] = *(const uint4*)(const void*)(kl + ga);
    }
    __syncthreads();
    // ---- QK^T: S[16 q][64 s], 3-term split ----
    f32x4 sc[4];
#pragma unroll
    for (int ct = 0; ct < 4; ct++) sc[ct] = (f32x4){0.f, 0.f, 0.f, 0.f};
#pragma unroll
    for (int ks = 0; ks < 4; ks++) {
#pragma unroll
      for (int ct = 0; ct < 4; ct++) {
        int ko = (ct * 16 + l15) * KLP + ks * 32 + quad * 8;
        bf16x8 kfh = *(const bf16x8*)(const void*)&KVh[ko];
        bf16x8 kfl = *(const bf16x8*)(const void*)&KVl[ko];
        sc[ct] = __builtin_amdgcn_mfma_f32_16x16x32_bf16(qfh[ks], kfh, sc[ct], 0, 0, 0);
        sc[ct] = __builtin_amdgcn_mfma_f32_16x16x32_bf16(qfl[ks], kfh, sc[ct], 0, 0, 0);
        sc[ct] = __builtin_amdgcn_mfma_f32_16x16x32_bf16(qfh[ks], kfl, sc[ct], 0, 0, 0);
      }
    }
    // ---- online softmax on C layout (col=lane&15 -> key, row=quad*4+r -> q) ----
    float pv[4][4];
    bool diag = (s0 == q0);
#pragma unroll
    for (int ct = 0; ct < 4; ct++)
#pragma unroll
      for (int r = 0; r < 4; r++) {
        float v = sc[ct][r] * scale;
        if (diag && (ct * 16 + l15 > wid * 16 + quad * 4 + r)) v = -1e30f;
        pv[ct][r] = v;
      }
    float al[4];
#pragma unroll
    for (int r = 0; r < 4; r++) {
      float mt = fmaxf(fmaxf(pv[0][r], pv[1][r]), fmaxf(pv[2][r], pv[3][r]));
#pragma unroll
      for (int off = 1; off < 16; off <<= 1) mt = fmaxf(mt, __shfl_xor(mt, off, 64));
      float mn = fmaxf(m[r], mt);
      al[r] = __expf(m[r] - mn);
      m[r] = mn;
      float rs = 0.f;
#pragma unroll
      for (int ct = 0; ct < 4; ct++) {
        pv[ct][r] = __expf(pv[ct][r] - mn);
        rs += pv[ct][r];
      }
#pragma unroll
      for (int off = 1; off < 16; off <<= 1) rs += __shfl_xor(rs, off, 64);
      l[r] = l[r] * al[r] + rs;
    }
    f32x4 av = {al[0], al[1], al[2], al[3]};
#pragma unroll
    for (int i = 0; i < 8; i++) o[i] *= av;
    // ---- P -> LDS (bf16), per-wave private (written+read by same wave) ----
#pragma unroll
    for (int ct = 0; ct < 4; ct++)
#pragma unroll
      for (int r = 0; r < 4; r++)
        Ps[wid][(quad * 4 + r) * PLP + ct * 16 + l15] = (short)f2bf(pv[ct][r]);
    __syncthreads();  // all QK^T K-reads done before V overwrites buffer
    // ---- stage V^T hi/lo: 128 rows x 64 shorts each ----
#pragma unroll
    for (int it = 0; it < 4; it++) {
      int c = it * 256 + tid;
      int r = c >> 3, off = (c & 7) * 8;
      size_t ga = (size_t)(g * HD + r) * T_DIM + s0 + off;
      *(uint4*)(void*)&KVh[r * VLP + off] = *(const uint4*)(const void*)(vh + ga);
      *(uint4*)(void*)&KVl[r * VLP + off] = *(const uint4*)(const void*)(vl + ga);
    }
    __syncthreads();
    // ---- PV: O[16 q][128 d] += P (Vhi + Vlo) ----
#pragma unroll
    for (int ks = 0; ks < 2; ks++) {
      bf16x8 pf = *(const bf16x8*)(const void*)&Ps[wid][l15 * PLP + ks * 32 + quad * 8];
#pragma unroll
      for (int ct = 0; ct < 8; ct++) {
        int vo = (ct * 16 + l15) * VLP + ks * 32 + quad * 8;
        bf16x8 vfh = *(const bf16x8*)(const void*)&KVh[vo];
        bf16x8 vfl = *(const bf16x8*)(const void*)&KVl[vo];
        o[ct] = __builtin_amdgcn_mfma_f32_16x16x32_bf16(pf, vfh, o[ct], 0, 0, 0);
        o[ct] = __builtin_amdgcn_mfma_f32_16x16x32_bf16(pf, vfl, o[ct], 0, 0, 0);
      }
    }
  }
  // ---- epilogue: normalize, write bf16 hi+lo ----
  float inv[4];
#pragma unroll
  for (int r = 0; r < 4; r++) inv[r] = 1.f / l[r];
#pragma unroll
  for (int ct = 0; ct < 8; ct++)
#pragma unroll
    for (int r = 0; r < 4; r++) {
      float v = o[ct][r] * inv[r];
      unsigned short hi = f2bf(v);
      unsigned short lo = f2bf(v - bf2f(hi));
      int t = q0 + wid * 16 + quad * 4 + r;
      size_t oi = (size_t)t * QS + h * HD + ct * 16 + l15;
      ohi[oi] = hi;
      olo[oi] = lo;
    }
}

// ---------------- router: logits = y @ router_w (fp32!), top-1 + sigmoid ----------------
__global__ __launch_bounds__(256) void router_kernel(const float* __restrict__ y,
                                                     const float* __restrict__ rw,
                                                     int* __restrict__ eidx,
                                                     float* __restrict__ gate) {
  int t = blockIdx.x, tid = threadIdx.x;
  const float* row = y + (size_t)t * H_DIM;
  float4 xa = *(const float4*)(row + tid * 8);
  float4 xb = *(const float4*)(row + tid * 8 + 4);
  float xv[8] = {xa.x, xa.y, xa.z, xa.w, xb.x, xb.y, xb.z, xb.w};
  float acc[8] = {0, 0, 0, 0, 0, 0, 0, 0};
#pragma unroll
  for (int i = 0; i < 8; i++) {
    const float* r8 = rw + (size_t)(tid * 8 + i) * 8;
    float4 ra = *(const float4*)(r8);
    float4 rb = *(const float4*)(r8 + 4);
    acc[0] = fmaf(xv[i], ra.x, acc[0]);
    acc[1] = fmaf(xv[i], ra.y, acc[1]);
    acc[2] = fmaf(xv[i], ra.z, acc[2]);
    acc[3] = fmaf(xv[i], ra.w, acc[3]);
    acc[4] = fmaf(xv[i], rb.x, acc[4]);
    acc[5] = fmaf(xv[i], rb.y, acc[5]);
    acc[6] = fmaf(xv[i], rb.z, acc[6]);
    acc[7] = fmaf(xv[i], rb.w, acc[7]);
  }
  __shared__ float red[4][8];
  int lane = tid & 63, wid = tid >> 6;
#pragma unroll
  for (int e = 0; e < 8; e++) acc[e] = waveReduceSum(acc[e]);
  if (lane == 0) {
#pragma unroll
    for (int e = 0; e < 8; e++) red[wid][e] = acc[e];
  }
  __syncthreads();
  if (tid == 0) {
    float best = -1e30f;
    int be = 0;
#pragma unroll
    for (int e = 0; e < 8; e++) {
      float v = red[0][e] + red[1][e] + red[2][e] + red[3][e];
      if (v > best) { best = v; be = e; }
    }
    eidx[t] = be;
    gate[t] = 1.f / (1.f + expf(-best));
  }
}

// ---------------- MoE routing bookkeeping (128-row padding per expert) ----------------
__global__ void moe_prep(int* counts, int* cursor, int* perm) {
  int tid = threadIdx.x;
  if (tid < 8) { counts[tid] = 0; cursor[tid] = 0; }
  for (int i = tid; i < PADMAX; i += 256) perm[i] = -1;
}
__global__ void hist_kernel(const int* __restrict__ eidx, int* counts) {
  int t = blockIdx.x * 256 + threadIdx.x;
  atomicAdd(&counts[eidx[t]], 1);
}
__global__ void scan_kernel(const int* __restrict__ counts, int* poff, int* rbmap) {
  if (threadIdx.x == 0 && blockIdx.x == 0) {
    int off = 0;
    for (int e = 0; e < 8; e++) {
      poff[e] = off;
      off += ((counts[e] + 127) >> 7) << 7;
    }
    poff[8] = off;
    int nRB = off >> 7;
    for (int rb = 0; rb < MAXRB; rb++) {
      int ee = -1;
      if (rb < nRB) {
        int r0 = rb * 128;
        for (int e = 0; e < 8; e++)
          if (r0 >= poff[e] && r0 < poff[e + 1]) ee = e;
      }
      rbmap[rb] = ee;
    }
  }
}
__global__ void scatter_kernel(const int* __restrict__ eidx, const int* __restrict__ poff,
                               int* cursor, int* perm) {
  int t = blockIdx.x * 256 + threadIdx.x;
  int e = eidx[t];
  int pos = poff[e] + atomicAdd(&cursor[e], 1);
  perm[pos] = t;
}

// ---------------- bf16 MFMA GEMM: 128x128x32 tile, 256 thr (4 waves 2x2) ----------------
// A: bf16 (hi[,lo]) M-major; B: fp32 [K][N] global, converted to bf16 in staging.
// SPLIT: 3-term bf16x2 product (fp32-class accuracy). DUAL: second B (gate+up).
// GROUPED: B += rbmap[mb]*bStride; GATHER_A: A row via perm (-1 -> zeros).
template <int STORE, bool DUAL, bool GROUPED, bool GATHER_A, bool SPLIT>
__global__ __launch_bounds__(256) void gemm_mfma(
    const ushort* __restrict__ Ahi, const ushort* __restrict__ Alo,
    const float* __restrict__ B0, const float* __restrict__ B1g,
    float* __restrict__ C, ushort* __restrict__ C16,
    const float* __restrict__ resid, int K, int N,
    const int* __restrict__ perm, const int* __restrict__ rbmap,
    const float* __restrict__ gate, size_t bStride) {
  __shared__ short As[(SPLIT ? 2 : 1) * BM * LP];
  __shared__ short Bs[((SPLIT || DUAL) ? 2 : 1) * BM * LP];
  short* As2 = As + BM * LP;  // A lo
  short* Bs2 = Bs + BM * LP;  // B lo, or B1 (dual)
  int tid = threadIdx.x;
  int mb = blockIdx.y, nb = blockIdx.x;
  const float* b0 = B0;
  const float* b1 = B1g;
  if constexpr (GROUPED) {
    int e = rbmap[mb];
    if (e < 0) return;  // uniform exit before any barrier
    b0 += (size_t)e * bStride;
    if constexpr (DUAL) b1 += (size_t)e * bStride;
  }
  // A staging: thread -> (row am, k-half), 16 contiguous bf16 each
  int am = tid >> 1, ak = (tid & 1) * 16;
  const ushort* aP = nullptr;
  const ushort* aPlo = nullptr;
  {
    int grow = mb * BM + am;
    if constexpr (GATHER_A) {
      int tk = perm[grow];
      if (tk >= 0) aP = Ahi + (size_t)tk * K + ak;
    } else {
      aP = Ahi + (size_t)grow * K + ak;
      if constexpr (SPLIT) aPlo = Alo + (size_t)grow * K + ak;
    }
  }
  // B staging: thread -> (4 k-rows at kq*4, 4 n-cols at n4*4); transpose to [n][k] in LDS
  int n4 = tid & 31, kq = tid >> 5;
  const float* bP0 = b0 + (size_t)(kq * 4) * N + nb * BN + n4 * 4;
  const float* bP1 = DUAL ? (b1 + (size_t)(kq * 4) * N + nb * BN + n4 * 4) : nullptr;
  int lane = tid & 63, wv = tid >> 6;
  int wM = (wv >> 1) * 64, wN = (wv & 1) * 64;
  int l15 = lane & 15, quad = lane >> 4;
  f32x4 acc0[4][4];
  f32x4 acc1[4][4];
#pragma unroll
  for (int i = 0; i < 4; i++)
#pragma unroll
    for (int j = 0; j < 4; j++) {
      acc0[i][j] = (f32x4){0.f, 0.f, 0.f, 0.f};
      if constexpr (DUAL) acc1[i][j] = (f32x4){0.f, 0.f, 0.f, 0.f};
    }
  for (int k0 = 0; k0 < K; k0 += BK) {
    // ---- stage A ----
    {
      uint4 v0, v1;
      if (aP) {
        v0 = *(const uint4*)(const void*)(aP + k0);
        v1 = *(const uint4*)(const void*)(aP + k0 + 8);
      } else {
        v0 = make_uint4(0, 0, 0, 0);
        v1 = v0;
      }
      *(uint4*)(void*)&As[am * LP + ak] = v0;
      *(uint4*)(void*)&As[am * LP + ak + 8] = v1;
      if constexpr (SPLIT) {
        uint4 w0 = *(const uint4*)(const void*)(aPlo + k0);
        uint4 w1 = *(const uint4*)(const void*)(aPlo + k0 + 8);
        *(uint4*)(void*)&As2[am * LP + ak] = w0;
        *(uint4*)(void*)&As2[am * LP + ak + 8] = w1;
      }
    }
    // ---- stage B (transpose + fp32->bf16) ----
    {
      float bv[4][4];
#pragma unroll
      for (int i = 0; i < 4; i++) {
        float4 t = *(const float4*)(bP0 + (size_t)(k0 + i) * N);
        bv[i][0] = t.x; bv[i][1] = t.y; bv[i][2] = t.z; bv[i][3] = t.w;
      }
#pragma unroll
      for (int j = 0; j < 4; j++) {
        ushort4 p = make_ushort4(f2bf(bv[0][j]), f2bf(bv[1][j]), f2bf(bv[2][j]), f2bf(bv[3][j]));
        *(ushort4*)(void*)&Bs[(n4 * 4 + j) * LP + kq * 4] = p;
        if constexpr (SPLIT) {
          ushort4 q = make_ushort4(f2bf(bv[0][j] - bf2f(p.x)), f2bf(bv[1][j] - bf2f(p.y)),
                                   f2bf(bv[2][j] - bf2f(p.z)), f2bf(bv[3][j] - bf2f(p.w)));
          *(ushort4*)(void*)&Bs2[(n4 * 4 + j) * LP + kq * 4] = q;
        }
      }
      if constexpr (DUAL) {
        float cv[4][4];
#pragma unroll
        for (int i = 0; i < 4; i++) {
          float4 t = *(const float4*)(bP1 + (size_t)(k0 + i) * N);
          cv[i][0] = t.x; cv[i][1] = t.y; cv[i][2] = t.z; cv[i][3] = t.w;
        }
#pragma unroll
        for (int j = 0; j < 4; j++) {
          ushort4 p = make_ushort4(f2bf(cv[0][j]), f2bf(cv[1][j]), f2bf(cv[2][j]), f2bf(cv[3][j]));
          *(ushort4*)(void*)&Bs2[(n4 * 4 + j) * LP + kq * 4] = p;
        }
      }
    }
    __syncthreads();
    // ---- fragments + MFMA ----
    {
      const short* aB = &As[(wM + l15) * LP + quad * 8];
      const short* bB = &Bs[(wN + l15) * LP + quad * 8];
      bf16x8 af[4], bf_[4];
#pragma unroll
      for (int i = 0; i < 4; i++) af[i] = *(const bf16x8*)(const void*)(aB + i * 16 * LP);
#pragma unroll
      for (int i = 0; i < 4; i++) bf_[i] = *(const bf16x8*)(const void*)(bB + i * 16 * LP);
      if constexpr (SPLIT) {
        const short* aB2 = &As2[(wM + l15) * LP + quad * 8];
        const short* bB2 = &Bs2[(wN + l15) * LP + quad * 8];
        bf16x8 afl[4], bfl[4];
#pragma unroll
        for (int i = 0; i < 4; i++) afl[i] = *(const bf16x8*)(const void*)(aB2 + i * 16 * LP);
#pragma unroll
        for (int i = 0; i < 4; i++) bfl[i] = *(const bf16x8*)(const void*)(bB2 + i * 16 * LP);
#pragma unroll
        for (int rt = 0; rt < 4; rt++)
#pragma unroll
          for (int ct = 0; ct < 4; ct++) {
            acc0[rt][ct] = __builtin_amdgcn_mfma_f32_16x16x32_bf16(af[rt], bf_[ct], acc0[rt][ct], 0, 0, 0);
            acc0[rt][ct] = __builtin_amdgcn_mfma_f32_16x16x32_bf16(afl[rt], bf_[ct], acc0[rt][ct], 0, 0, 0);
            acc0[rt][ct] = __builtin_amdgcn_mfma_f32_16x16x32_bf16(af[rt], bfl[ct], acc0[rt][ct], 0, 0, 0);
          }
      } else if constexpr (DUAL) {
        const short* bB2 = &Bs2[(wN + l15) * LP + quad * 8];
        bf16x8 bu[4];
#pragma unroll
        for (int i = 0; i < 4; i++) bu[i] = *(const bf16x8*)(const void*)(bB2 + i * 16 * LP);
#pragma unroll
        for (int rt = 0; rt < 4; rt++)
#pragma unroll
          for (int ct = 0; ct < 4; ct++) {
            acc0[rt][ct] = __builtin_amdgcn_mfma_f32_16x16x32_bf16(af[rt], bf_[ct], acc0[rt][ct], 0, 0, 0);
            acc1[rt][ct] = __builtin_amdgcn_mfma_f32_16x16x32_bf16(af[rt], bu[ct], acc1[rt][ct], 0, 0, 0);
          }
      } else {
#pragma unroll
        for (int rt = 0; rt < 4; rt++)
#pragma unroll
          for (int ct = 0; ct < 4; ct++)
            acc0[rt][ct] = __builtin_amdgcn_mfma_f32_16x16x32_bf16(af[rt], bf_[ct], acc0[rt][ct], 0, 0, 0);
      }
    }
    __syncthreads();
  }
  // ---- epilogue: C/D layout col=lane&15, row=quad*4+reg ----
#pragma unroll
  for (int rt = 0; rt < 4; rt++) {
#pragma unroll
    for (int r = 0; r < 4; r++) {
      int row = mb * BM + wM + rt * 16 + quad * 4 + r;
      if constexpr (STORE == ST_SCATTER) {
        int tk = perm[row];
        if (tk < 0) continue;
        float g = gate[tk];
        size_t base = (size_t)tk * N;
#pragma unroll
        for (int ct = 0; ct < 4; ct++) {
          int col = nb * BN + wN + ct * 16 + l15;
          C[base + col] += g * acc0[rt][ct][r];
        }
      } else {
        size_t base = (size_t)row * N;
#pragma unroll
        for (int ct = 0; ct < 4; ct++) {
          int col = nb * BN + wN + ct * 16 + l15;
          float v = acc0[rt][ct][r];
          if constexpr (STORE == ST_PLAIN) {
            C[base + col] = v;
          } else if constexpr (STORE == ST_RESID) {
            C[base + col] = resid[base + col] + v;
          } else if constexpr (STORE == ST_ACCUM) {
            C[base + col] += v;
          } else if constexpr (STORE == ST_SILU) {
            float u = acc1[rt][ct][r];
            float hv = v / (1.f + __expf(-v)) * u;
            C16[base + col] = f2bf(hv);
          }
        }
      }
    }
  }
}

extern "C" void kernel_launch(void* const* d_in, const int* in_sizes, int n_in,
                              void* d_out, int out_size, void* d_ws, size_t ws_size,
                              hipStream_t stream) {
  const int* positions = (const int*)d_in[0];
  const float* hidden = (const float*)d_in[1];
  const float* ln1 = (const float*)d_in[2];
  const float* ln2 = (const float*)d_in[3];
  const float* w_qkv = (const float*)d_in[4];
  const float* w_o = (const float*)d_in[5];
  const float* qnw = (const float*)d_in[6];
  const float* knw = (const float*)d_in[7];
  const float* rw = (const float*)d_in[8];
  const float* wsg = (const float*)d_in[9];
  const float* wsu = (const float*)d_in[10];
  const float* wsd = (const float*)d_in[11];
  const float* weg = (const float*)d_in[12];
  const float* weu = (const float*)d_in[13];
  const float* wed = (const float*)d_in[14];
  float* out = (float*)d_out;
  float* ws = (float*)d_ws;

  // workspace layout (floats); total ~16.8M floats = 67.2 MB
  // [0, 6.29M): qkv f32 (phase1) -> hbuf bf16 3072x4096 (phase2, exact alias)
  float* qkv = ws;
  ushort* hbuf = (ushort*)ws;
  // [6.29M, 10.49M): x1 hi/lo bf16 (phase1) -> attn hi/lo bf16 (after qkv GEMM)
  ushort* x1h = (ushort*)(ws + 6291456);
  ushort* x1l = (ushort*)(ws + 6291456 + 2097152);
  ushort* ath = x1h;
  ushort* atl = x1l;
  // [10.49M, 16.78M): during attention phase: Q/K/Vt bf16 hi+lo (exactly fills region);
  // afterwards re-used as ybuf f32 + yb16 (step 6+).
  ushort* qbh = (ushort*)(ws + 10485760);
  ushort* qbl = (ushort*)(ws + 12582912);
  ushort* kbh = (ushort*)(ws + 14680064);
  ushort* kbl = (ushort*)(ws + 15204352);
  ushort* vth = (ushort*)(ws + 15728640);
  ushort* vtl = (ushort*)(ws + 16252928);
  float* ybuf = ws + 10485760;
  ushort* yb16 = (ushort*)(ws + 14680064);
  // misc
  int* eidx = (int*)(ws + 16777216);
  float* gatew = (float*)(eidx + T_DIM);
  int* counts = (int*)(gatew + T_DIM);
  int* cursor = counts + 8;
  int* poff = cursor + 8;
  int* rbmap = poff + 16;
  int* perm = rbmap + 32;  // PADMAX ints

  // 1. x1 = rmsnorm(hidden, ln1) -> bf16 hi+lo
  rmsnorm_kernel<false, true><<<T_DIM, 256, 0, stream>>>(hidden, ln1, nullptr, x1h, x1l);
  // 2. qkv = x1 @ w_qkv  (split bf16x2, fp32-class)
  gemm_mfma<ST_PLAIN, false, false, false, true><<<dim3(QKV_N / BN, T_DIM / BM), 256, 0, stream>>>(
      x1h, x1l, w_qkv, nullptr, qkv, nullptr, nullptr, H_DIM, QKV_N, nullptr, nullptr, nullptr, 0);
  // 3. rope + q/k rmsnorm -> bf16 hi/lo buffers (qkv fp32 untouched)
  rope_norm_kernel<<<T_DIM, 256, 0, stream>>>(qkv, positions, qnw, knw, qbh, qbl, kbh, kbl);
  // 3b. V transpose -> bf16 hi/lo [d][t]
  vtrans_kernel<<<KVS, 256, 0, stream>>>(qkv, vth, vtl);
  // 4. attention (MFMA flash) -> bf16 hi+lo
  attn_mfma<<<512, 256, 0, stream>>>(qbh, qbl, kbh, kbl, vth, vtl, ath, atl);
  // 5. out = hidden + attn @ w_o  (split)
  gemm_mfma<ST_RESID, false, false, false, true><<<dim3(H_DIM / BN, T_DIM / BM), 256, 0, stream>>>(
      ath, atl, w_o, nullptr, out, nullptr, hidden, QS, H_DIM, nullptr, nullptr, nullptr, 0);
  // 6. y = rmsnorm(out, ln2) -> fp32 (router) + bf16 (GEMMs)
  rmsnorm_kernel<true, false><<<T_DIM, 256, 0, stream>>>(out, ln2, ybuf, yb16, nullptr);
  // 7. router top-1 (fp32 logits: selection must match reference)
  router_kernel<<<T_DIM, 256, 0, stream>>>(ybuf, rw, eidx, gatew);
  // 8-11. routing bookkeeping (128-row padding)
  moe_prep<<<1, 256, 0, stream>>>(counts, cursor, perm);
  hist_kernel<<<T_DIM / 256, 256, 0, stream>>>(eidx, counts);
  scan_kernel<<<1, 64, 0, stream>>>(counts, poff, rbmap);
  scatter_kernel<<<T_DIM / 256, 256, 0, stream>>>(eidx, poff, cursor, perm);
  // 12. expert gate/up (gather rows, grouped B) -> hbuf bf16
  gemm_mfma<ST_SILU, true, true, true, false><<<dim3(I_DIM / BN, MAXRB), 256, 0, stream>>>(
      yb16, nullptr, weg, weu, nullptr, hbuf, nullptr, H_DIM, I_DIM, perm, rbmap, nullptr,
      (size_t)H_DIM * I_DIM);
  // 13. expert down, gated scatter-add into out
  gemm_mfma<ST_SCATTER, false, true, false, false><<<dim3(H_DIM / BN, MAXRB), 256, 0, stream>>>(
      hbuf, nullptr, wed, nullptr, out, nullptr, nullptr, I_DIM, H_DIM, perm, rbmap, gatew,
      (size_t)I_DIM * H_DIM);
  // 14. shared gate/up -> hbuf (rows 0..T, overwrites expert h after it's consumed)
  gemm_mfma<ST_SILU, true, false, false, false><<<dim3(I_DIM / BN, T_DIM / BM), 256, 0, stream>>>(
      yb16, nullptr, wsg, wsu, nullptr, hbuf, nullptr, H_DIM, I_DIM, nullptr, nullptr, nullptr, 0);
  // 15. out += shared_h @ ws_down
  gemm_mfma<ST_ACCUM, false, false, false, false><<<dim3(H_DIM / BN, T_DIM / BM), 256, 0, stream>>>(
      hbuf, nullptr, wsd, nullptr, out, nullptr, nullptr, I_DIM, H_DIM, nullptr, nullptr, nullptr, 0);

  (void)in_sizes; (void)n_in; (void)out_size; (void)ws_size;
}